// Round 11
// baseline (1001.800 us; speedup 1.0000x reference)
//
#include <hip/hip_runtime.h>
#include <hip/hip_fp16.h>

#define BN 13248
#define NE 211968
#define NBKT 8        // source buckets (src>>11 -> 0..6); approx locality sort
#define ZSTRIDE 200   // halves per Z row (192 + 8 pad)
#define HSTRIDE 40    // halves per hb16 tau-row (32 + 8 pad)
#define HNODE 480     // 12 rows * 40

typedef __attribute__((ext_vector_type(8))) short bf16x8;
typedef __attribute__((ext_vector_type(8))) _Float16 f16x8;
typedef __attribute__((ext_vector_type(4))) float f32x4;

__device__ __forceinline__ f32x4 mfma16b(bf16x8 a, bf16x8 b, f32x4 c) {
  return __builtin_amdgcn_mfma_f32_16x16x32_bf16(a, b, c, 0, 0, 0);
}
__device__ __forceinline__ f32x4 mfma16h(f16x8 a, f16x8 b, f32x4 c) {
  return __builtin_amdgcn_mfma_f32_16x16x32_f16(a, b, c, 0, 0, 0);
}

__device__ __forceinline__ unsigned short to_bf16(float v) {
  unsigned bits = __float_as_uint(v);
  return (unsigned short)((bits + 0x7FFFu + ((bits >> 16) & 1u)) >> 16);
}
__device__ __forceinline__ unsigned short to_f16(float v) {
  union { __half h; unsigned short s; } u; u.h = __float2half(v); return u.s;
}
__device__ __forceinline__ unsigned h2u(__half2 h) {
  union { __half2 h; unsigned u; } v; v.h = h; return v.u;
}
__device__ __forceinline__ __half2 u2h(unsigned u) {
  union { unsigned u; __half2 h; } v; v.u = u; return v.h;
}

__device__ __forceinline__ float fast_tanh(float x) {
  float e2 = __expf(2.f * x);
  return 1.f - 2.f / (e2 + 1.f);
}
__device__ __forceinline__ float fast_sig(float x) {
  return 1.f / (1.f + __expf(-x));
}

// ---------------- CSR build (bucketed by source octile for L2 locality) ----------------
__global__ void k_count(const int* __restrict__ src, const int* __restrict__ dst,
                        int* __restrict__ cur_f, int* __restrict__ cur_b) {
  int e = blockIdx.x * 256 + threadIdx.x;
  if (e < NE) {
    int s = src[e], t = dst[e];
    atomicAdd(&cur_f[t * NBKT + (s >> 11)], 1);
    atomicAdd(&cur_b[s * NBKT + (t >> 11)], 1);
  }
}

__global__ void k_scan(int* __restrict__ cnt_f, int* __restrict__ row_f,
                       int* __restrict__ cnt_b, int* __restrict__ row_b) {
  __shared__ int sdata[1024];
  const int TOT = BN * NBKT;            // 105984
  const int PER = (TOT + 1023) / 1024;  // 104
  int tid = threadIdx.x;
  for (int which = 0; which < 2; ++which) {
    int* cnt = which ? cnt_b : cnt_f;
    int* row = which ? row_b : row_f;
    int base = tid * PER;
    int tot = 0;
    for (int k = 0; k < PER; ++k) {
      int idx = base + k;
      if (idx < TOT) tot += cnt[idx];
    }
    sdata[tid] = tot;
    __syncthreads();
    for (int off = 1; off < 1024; off <<= 1) {
      int add = (tid >= off) ? sdata[tid - off] : 0;
      __syncthreads();
      sdata[tid] += add;
      __syncthreads();
    }
    int running = sdata[tid] - tot;  // exclusive
    for (int k = 0; k < PER; ++k) {
      int idx = base + k;
      if (idx < TOT) {
        int v = cnt[idx];
        if ((idx & (NBKT - 1)) == 0) row[idx / NBKT] = running;
        cnt[idx] = running;
        running += v;
      }
    }
    if (tid == 1023) row[BN] = NE;
    __syncthreads();
  }
}

// edge record: {col, h2(w), h2(w^2), h2(w^3)}
__global__ void k_fill(const int* __restrict__ src, const int* __restrict__ dst,
                       const float* __restrict__ w,
                       int* __restrict__ cur_f, int4* __restrict__ ce_f,
                       int* __restrict__ cur_b, int4* __restrict__ ce_b) {
  int e = blockIdx.x * 256 + threadIdx.x;
  if (e < NE) {
    int s = src[e], t = dst[e];
    float wv = w[e];
    float w2 = wv * wv, w3 = w2 * wv;
    int u1 = (int)h2u(__float2half2_rn(wv));
    int u2 = (int)h2u(__float2half2_rn(w2));
    int u3 = (int)h2u(__float2half2_rn(w3));
    int p = atomicAdd(&cur_f[t * NBKT + (s >> 11)], 1); ce_f[p] = make_int4(s, u1, u2, u3);
    int q = atomicAdd(&cur_b[s * NBKT + (t >> 11)], 1); ce_b[q] = make_int4(t, u1, u2, u3);
  }
}

// ---------------- init linear ----------------
__global__ void k_init(const float* __restrict__ x, const float* __restrict__ iw,
                       const float* __restrict__ ib, float* __restrict__ h) {
  int idx = blockIdx.x * 256 + threadIdx.x;
  if (idx >= BN * 13 * 32) return;
  int c = idx & 31;
  int r = idx >> 5;          // r = tau*BN + n
  int n = r % BN;
  int tau = r / BN;
  float x0 = x[(n * 13 + tau) * 2 + 0];
  float x1 = x[(n * 13 + tau) * 2 + 1];
  h[idx] = fmaf(x0, iw[c], fmaf(x1, iw[32 + c], ib[c]));
}

// ---------------- weight pre-pack ----------------
__global__ void k_pack(const float* __restrict__ skip_w, const float* __restrict__ skip_b,
                       const float* __restrict__ w0, const float* __restrict__ w1,
                       const float* __restrict__ gcn_w,
                       const float* __restrict__ filt_w, const float* __restrict__ gate_w,
                       unsigned short* __restrict__ SWb, unsigned short* __restrict__ W0T,
                       unsigned short* __restrict__ W1T, float* __restrict__ bsum,
                       unsigned short* __restrict__ Gg16, unsigned short* __restrict__ WTC) {
  int id = blockIdx.x * 256 + threadIdx.x;
  if (id < 65536) {          // SWb[j][k=l*32+c] = skip_w[l][j][c]  (bf16, head)
    int j = id >> 8, k = id & 255;
    SWb[id] = to_bf16(skip_w[((k >> 5) * 256 + j) * 32 + (k & 31)]);
  }
  if (id < 131072) {         // W0T[jo][k] = w0[k][jo]  (bf16, head)
    int jo = id >> 8, k = id & 255;
    W0T[id] = to_bf16(w0[k * 512 + jo]);
  }
  if (id < 8192) {           // W1T[n][k] = w1[k][n], n padded to 16  (bf16, head)
    int n = id >> 9, k = id & 511;
    W1T[id] = (n < 12) ? to_bf16(w1[k * 12 + n]) : (unsigned short)0;
  }
  if (id < 256) {
    float s = 0.f;
    for (int l = 0; l < 8; ++l) s += skip_b[l * 256 + id];
    bsum[id] = s;
  }
  if (id < 49152) {          // Gg16[l][co][k=a*32+ci] = gcn_w[l][a][ci][co]  (fp16)
    int l = id / 6144, rem = id % 6144;
    int co = rem / 192, k = rem % 192;
    int a = k >> 5, ci = k & 31;
    Gg16[id] = to_f16(gcn_w[((l * 6 + a) * 32 + ci) * 32 + co]);
  }
  if (id < 32768) {          // WTC[l][g][co][k=64]: B^T for TCN MFMA (fp16)
    int l = id >> 12, rem = id & 4095;
    int g = rem >> 11, co = (rem >> 6) & 31, k = rem & 63;
    const float* srcw = (g ? gate_w : filt_w) + l * 2048;
    float v = (k < 32) ? srcw[(co * 32 + k) * 2 + 0] : srcw[(co * 32 + (k - 32)) * 2 + 1];
    WTC[id] = to_f16(v);
  }
}

// ---------------- standalone gated TCN (layer 0 only): fp16 t out ----------------
template<int LIN, int D, int TPAD>
__global__ __launch_bounds__(256) void k_tcn(const float* __restrict__ h_in, unsigned short* __restrict__ t_out,
    const float* __restrict__ fw, const float* __restrict__ fb,
    const float* __restrict__ gw, const float* __restrict__ gb) {
  constexpr int LOUT = LIN - D;
  __shared__ __align__(16) float wq[32 * 32 * 4];
  __shared__ float hl[8][LIN * 32];
  int tid = threadIdx.x;
  for (int f = tid; f < 4096; f += 256) {
    int e = f & 3, co = (f >> 2) & 31, ci = f >> 7;
    const float* srcw = (e < 2) ? fw : gw;
    wq[f] = srcw[(co * 32 + ci) * 2 + (e & 1)];
  }
  int n0 = blockIdx.x * 8;
  for (int i = tid; i < 8 * LIN * 32; i += 256) {
    int c = i & 31, r = i >> 5;
    int nl = r / LIN, tau = r % LIN;
    hl[nl][tau * 32 + c] = h_in[(tau * BN + n0 + nl) * 32 + c];
  }
  __syncthreads();
  int nl = tid >> 5, co = tid & 31;
  int n = n0 + nl;
  float accf[LOUT], accg[LOUT];
  float fbv = fb[co], gbv = gb[co];
#pragma unroll
  for (int j = 0; j < LOUT; ++j) { accf[j] = fbv; accg[j] = gbv; }
#pragma unroll
  for (int ci = 0; ci < 32; ++ci) {
    float4 wv = *(const float4*)&wq[(ci * 32 + co) * 4];
    float xr[LIN];
#pragma unroll
    for (int t = 0; t < LIN; ++t) xr[t] = hl[nl][t * 32 + ci];
#pragma unroll
    for (int j = 0; j < LOUT; ++j) {
      accf[j] = fmaf(xr[j], wv.x, accf[j]);
      accf[j] = fmaf(xr[j + D], wv.y, accf[j]);
      accg[j] = fmaf(xr[j], wv.z, accg[j]);
      accg[j] = fmaf(xr[j + D], wv.w, accg[j]);
    }
  }
#pragma unroll
  for (int j = 0; j < TPAD; ++j) {
    unsigned short v = 0;
    if (j < LOUT) v = to_f16(fast_tanh(accf[j < LOUT ? j : 0]) * fast_sig(accg[j < LOUT ? j : 0]));
    t_out[(n * TPAD + j) * 32 + co] = v;
  }
}

// ---------------- gather: skip loads of known-zero padded rows ----------------
template<int TPAD, int NT>
__device__ __forceinline__ void edge_fma(const int4& c, const uint2 (&u)[NT], __half2* A) {
  __half2 wh0 = u2h((unsigned)c.y), wh1 = u2h((unsigned)c.z), wh2 = u2h((unsigned)c.w);
#pragma unroll
  for (int j = 0; j < NT; ++j) {
    __half2 v0 = u2h(u[j].x), v1 = u2h(u[j].y);
    A[(0 * NT + j) * 2 + 0] = __hfma2(wh0, v0, A[(0 * NT + j) * 2 + 0]);
    A[(0 * NT + j) * 2 + 1] = __hfma2(wh0, v1, A[(0 * NT + j) * 2 + 1]);
    A[(1 * NT + j) * 2 + 0] = __hfma2(wh1, v0, A[(1 * NT + j) * 2 + 0]);
    A[(1 * NT + j) * 2 + 1] = __hfma2(wh1, v1, A[(1 * NT + j) * 2 + 1]);
    A[(2 * NT + j) * 2 + 0] = __hfma2(wh2, v0, A[(2 * NT + j) * 2 + 0]);
    A[(2 * NT + j) * 2 + 1] = __hfma2(wh2, v1, A[(2 * NT + j) * 2 + 1]);
  }
}

template<int TPAD, int NT, int LOUTT>
__device__ __forceinline__ void gather_dir(const unsigned short* __restrict__ t_in,
    int e0, int e1, const int4* __restrict__ ce, int rowoff0, int rowbase, __half2* A) {
  constexpr bool FULL = (LOUTT >= TPAD);
  constexpr int EB = 4;
  int e = e0;
  for (; e + EB <= e1; e += EB) {
    int4 c[EB];
    uint2 u[EB][NT];
#pragma unroll
    for (int k = 0; k < EB; ++k) c[k] = ce[e + k];
#pragma unroll
    for (int k = 0; k < EB; ++k) {
      const unsigned short* p = t_in + c[k].x * (TPAD * 32) + rowoff0;
#pragma unroll
      for (int j = 0; j < NT; ++j) {
        if (FULL || rowbase + j < LOUTT) u[k][j] = *(const uint2*)(p + j * 32);
        else u[k][j] = make_uint2(0u, 0u);
      }
    }
#pragma unroll
    for (int k = 0; k < EB; ++k) edge_fma<TPAD, NT>(c[k], u[k], A);
  }
  for (; e < e1; ++e) {
    int4 c = ce[e];
    uint2 u[NT];
    const unsigned short* p = t_in + c.x * (TPAD * 32) + rowoff0;
#pragma unroll
    for (int j = 0; j < NT; ++j) {
      if (FULL || rowbase + j < LOUTT) u[j] = *(const uint2*)(p + j * 32);
      else u[j] = make_uint2(0u, 0u);
    }
    edge_fma<TPAD, NT>(c, u, A);
  }
}

// ---------------- fused layer: agg (MFMA f16) + residual + next-layer TCN (MFMA f16) ----------------
template<int LOUT, int D, int TPAD, int D2, int TPAD2, bool LAST>
__global__ __launch_bounds__(128, 4) void k_fused(
    const unsigned short* __restrict__ t_in,
    const float* __restrict__ h_in, float* __restrict__ h_out,
    float* __restrict__ lastcol, unsigned short* __restrict__ t_next,
    const int* __restrict__ row_f, const int4* __restrict__ ce_f,
    const int* __restrict__ row_b, const int4* __restrict__ ce_b,
    const unsigned short* __restrict__ Wg,    // [32][192] fp16 B^T (agg)
    const float* __restrict__ bias,
    const unsigned short* __restrict__ Wtc,   // [2][32][64] fp16 B^T (next TCN)
    const float* __restrict__ fbn, const float* __restrict__ gbn) {
  constexpr int NT = TPAD / 4;
  constexpr int LOUT2 = LAST ? 1 : (LOUT - D2);
  constexpr int SBYTES = 4 * TPAD * ZSTRIDE * 2;
  __shared__ __align__(16) char smem[SBYTES];
  unsigned short* Zl = (unsigned short*)smem;
  unsigned short* hb16 = (unsigned short*)smem;    // reused after agg-MFMA
  int tid = threadIdx.x;
  int nl = tid >> 5, lane32 = tid & 31;
  int tl = lane32 >> 3;
  int c4 = (lane32 & 7) << 2;
  int n0 = blockIdx.x * 4;
  int n = n0 + nl;
  int rowbase = tl * NT;
  int rowoff0 = rowbase * 32 + c4;
  int ef0 = row_f[n], ef1 = row_f[n + 1];
  int eb0 = row_b[n], eb1 = row_b[n + 1];
  __half2 acc[6 * NT * 2];
  __half2 zero = __float2half2_rn(0.f);
#pragma unroll
  for (int i = 0; i < 6 * NT * 2; ++i) acc[i] = zero;
  gather_dir<TPAD, NT, LOUT>(t_in, ef0, ef1, ce_f, rowoff0, rowbase, acc);
  gather_dir<TPAD, NT, LOUT>(t_in, eb0, eb1, ce_b, rowoff0, rowbase, acc + 3 * NT * 2);
#pragma unroll
  for (int j = 0; j < NT; ++j) {
    int m = nl * TPAD + rowbase + j;
#pragma unroll
    for (int a = 0; a < 6; ++a) {
      uint2 v = make_uint2(h2u(acc[(a * NT + j) * 2 + 0]), h2u(acc[(a * NT + j) * 2 + 1]));
      *(uint2*)(&Zl[m * ZSTRIDE + a * 32 + c4]) = v;
    }
  }
  __syncthreads();
  // agg MFMA: D[4*TPAD rows][32 co] = Z[4*TPAD][192] @ Wg[192][32]
  int wave = tid >> 6, lane = tid & 63;
  int m16 = lane & 15, q = lane >> 4;
  f32x4 dacc[NT];
#pragma unroll
  for (int i = 0; i < NT; ++i) {
    int u = wave * NT + i;
    int mt = u >> 1, nt = u & 1;
    dacc[i] = (f32x4){0.f, 0.f, 0.f, 0.f};
#pragma unroll
    for (int ks = 0; ks < 6; ++ks) {
      f16x8 av = *(const f16x8*)(&Zl[(mt * 16 + m16) * ZSTRIDE + ks * 32 + q * 8]);
      f16x8 bv = *(const f16x8*)((const _Float16*)Wg + (nt * 16 + m16) * 192 + ks * 32 + q * 8);
      dacc[i] = mfma16h(av, bv, dacc[i]);
    }
  }
  __syncthreads();   // Zl dead; smem becomes hb16
#pragma unroll
  for (int i = 0; i < NT; ++i) {
    int u = wave * NT + i;
    int mt = u >> 1, nt = u & 1;
    int co = nt * 16 + m16;
    float bco = bias[co];
#pragma unroll
    for (int r = 0; r < 4; ++r) {
      int mm = mt * 16 + q * 4 + r;           // C/D: col=lane&15, row=q*4+r
      int node = mm / TPAD;
      int tau = mm % TPAD;
      if (tau < LOUT) {
        float rres = h_in[((tau + D) * BN + n0 + node) * 32 + co];
        float o = dacc[i][r] + bco + rres;
        h_out[(tau * BN + n0 + node) * 32 + co] = o;
        if (!LAST) hb16[node * HNODE + tau * HSTRIDE + co] = to_f16(o);
        if (tau == LOUT - 1) lastcol[(n0 + node) * 32 + co] = o;
      }
    }
  }
  if (!LAST) {
    __syncthreads();
    // TCN via MFMA: A row m16 = j (conv out step), K=64: [h[j][ci], h[j+D2][ci]]
#pragma unroll
    for (int i = 0; i < 4; ++i) {
      int u = wave * 4 + i;
      int node = u >> 1, ntc = u & 1;
      int co = ntc * 16 + m16;
      f32x4 df = (f32x4){0.f, 0.f, 0.f, 0.f};
      f32x4 dg = (f32x4){0.f, 0.f, 0.f, 0.f};
#pragma unroll
      for (int s = 0; s < 2; ++s) {
        f16x8 av = *(const f16x8*)(&hb16[node * HNODE + (m16 + s * D2) * HSTRIDE + q * 8]);
        f16x8 bvf = *(const f16x8*)((const _Float16*)Wtc + (0 * 32 + co) * 64 + s * 32 + q * 8);
        f16x8 bvg = *(const f16x8*)((const _Float16*)Wtc + (1 * 32 + co) * 64 + s * 32 + q * 8);
        df = mfma16h(av, bvf, df);
        dg = mfma16h(av, bvg, dg);
      }
      float fbv = fbn[co], gbv = gbn[co];
#pragma unroll
      for (int r = 0; r < 4; ++r) {
        int j = q * 4 + r;
        if (j < TPAD2) {
          unsigned short v = 0;
          if (j < LOUT2)
            v = to_f16(fast_tanh(df[r] + fbv) * fast_sig(dg[r] + gbv));
          t_next[((n0 + node) * TPAD2 + j) * 32 + co] = v;
        }
      }
    }
  }
}

// ------------- fused MFMA head (bf16) -------------
__device__ __forceinline__ bf16x8 ldsA(const unsigned short* buf, int stride, int row, int ks, int q) {
  int unit = ks * 4 + q;
  int addr = row * stride + ((unit ^ (row & 7)) << 3);
  return *(const bf16x8*)(buf + addr);
}

__global__ __launch_bounds__(256) void k_final(const float* __restrict__ lastcol,
    const unsigned short* __restrict__ SWb, const unsigned short* __restrict__ W0T,
    const unsigned short* __restrict__ W1T, const float* __restrict__ bsum,
    const float* __restrict__ b0, const float* __restrict__ b1,
    float* __restrict__ out) {
  __shared__ __align__(16) unsigned short Z[32 * 256];
  __shared__ __align__(16) unsigned short H[32 * 512];
  int tid = threadIdx.x;
  int wave = tid >> 6, lane = tid & 63;
  int m16 = lane & 15, q = lane >> 4;
  int n0 = blockIdx.x * 32;
#pragma unroll
  for (int it = 0; it < 32; ++it) {
    int id = it * 256 + tid;
    int m = id >> 8, k = id & 255;
    float v = lastcol[((k >> 5) * BN + n0 + m) * 32 + (k & 31)];
    Z[m * 256 + (((k >> 3) ^ (m & 7)) << 3) + (k & 7)] = to_bf16(v);
  }
  __syncthreads();
  f32x4 acc1[2][4];
#pragma unroll
  for (int mt = 0; mt < 2; ++mt)
#pragma unroll
    for (int i = 0; i < 4; ++i) acc1[mt][i] = (f32x4){0.f, 0.f, 0.f, 0.f};
#pragma unroll
  for (int ks = 0; ks < 8; ++ks) {
    bf16x8 a0 = ldsA(Z, 256, m16, ks, q);
    bf16x8 a1 = ldsA(Z, 256, 16 + m16, ks, q);
#pragma unroll
    for (int i = 0; i < 4; ++i) {
      int j = (wave * 4 + i) * 16 + m16;
      bf16x8 b = *(const bf16x8*)(SWb + j * 256 + ks * 32 + q * 8);
      acc1[0][i] = mfma16b(a0, b, acc1[0][i]);
      acc1[1][i] = mfma16b(a1, b, acc1[1][i]);
    }
  }
  __syncthreads();
#pragma unroll
  for (int i = 0; i < 4; ++i) {
    int j = (wave * 4 + i) * 16 + m16;
    float bs = bsum[j];
#pragma unroll
    for (int mt = 0; mt < 2; ++mt)
#pragma unroll
      for (int r = 0; r < 4; ++r) {
        int row = mt * 16 + q * 4 + r;
        float v = fmaxf(acc1[mt][i][r] + bs, 0.f);
        Z[row * 256 + (((j >> 3) ^ (row & 7)) << 3) + (j & 7)] = to_bf16(v);
      }
  }
  __syncthreads();
  f32x4 acc2[2][8];
#pragma unroll
  for (int mt = 0; mt < 2; ++mt)
#pragma unroll
    for (int i = 0; i < 8; ++i) acc2[mt][i] = (f32x4){0.f, 0.f, 0.f, 0.f};
#pragma unroll
  for (int ks = 0; ks < 8; ++ks) {
    bf16x8 a0 = ldsA(Z, 256, m16, ks, q);
    bf16x8 a1 = ldsA(Z, 256, 16 + m16, ks, q);
#pragma unroll
    for (int i = 0; i < 8; ++i) {
      int jo = (wave * 8 + i) * 16 + m16;
      bf16x8 b = *(const bf16x8*)(W0T + jo * 256 + ks * 32 + q * 8);
      acc2[0][i] = mfma16b(a0, b, acc2[0][i]);
      acc2[1][i] = mfma16b(a1, b, acc2[1][i]);
    }
  }
#pragma unroll
  for (int i = 0; i < 8; ++i) {
    int jo = (wave * 8 + i) * 16 + m16;
    float b0v = b0[jo];
#pragma unroll
    for (int mt = 0; mt < 2; ++mt)
#pragma unroll
      for (int r = 0; r < 4; ++r) {
        int row = mt * 16 + q * 4 + r;
        float v = fmaxf(acc2[mt][i][r] + b0v, 0.f);
        H[row * 512 + (((jo >> 3) ^ (row & 7)) << 3) + (jo & 7)] = to_bf16(v);
      }
  }
  __syncthreads();
  if (wave < 2) {
    f32x4 acc3 = (f32x4){0.f, 0.f, 0.f, 0.f};
#pragma unroll
    for (int ks = 0; ks < 16; ++ks) {
      bf16x8 a = ldsA(H, 512, wave * 16 + m16, ks, q);
      bf16x8 b = *(const bf16x8*)(W1T + m16 * 512 + ks * 32 + q * 8);
      acc3 = mfma16b(a, b, acc3);
    }
    if (m16 < 12) {
      float bv = b1[m16];
#pragma unroll
      for (int r = 0; r < 4; ++r)
        out[(n0 + wave * 16 + q * 4 + r) * 12 + m16] = acc3[r] + bv;
    }
  }
}

extern "C" void kernel_launch(void* const* d_in, const int* in_sizes, int n_in,
                              void* d_out, int out_size, void* d_ws, size_t ws_size,
                              hipStream_t stream) {
  const float* x      = (const float*)d_in[0];
  const int*   esrc   = (const int*)d_in[1];
  const int*   edst   = (const int*)d_in[2];
  const float* ew     = (const float*)d_in[3];
  const float* init_w = (const float*)d_in[4];
  const float* init_b = (const float*)d_in[5];
  const float* filt_w = (const float*)d_in[6];
  const float* filt_b = (const float*)d_in[7];
  const float* gate_w = (const float*)d_in[8];
  const float* gate_b = (const float*)d_in[9];
  const float* gcn_w  = (const float*)d_in[10];
  const float* gcn_b  = (const float*)d_in[11];
  const float* skip_w = (const float*)d_in[12];
  const float* skip_b = (const float*)d_in[13];
  const float* w0     = (const float*)d_in[14];
  const float* b0     = (const float*)d_in[15];
  const float* w1     = (const float*)d_in[16];
  const float* b1     = (const float*)d_in[17];
  float* out = (float*)d_out;

  float* base = (float*)d_ws;
  float* hA      = base;                        // 13*BN*32 f32
  float* hB      = hA + 13 * BN * 32;           // 13*BN*32 f32
  unsigned short* tA = (unsigned short*)(hB + 13 * BN * 32);  // 12*BN*32 halves
  unsigned short* tB = tA + 12 * BN * 32;                     // 12*BN*32 halves
  float* lastcol = (float*)(tB + 12 * BN * 32); // 8*BN*32 f32
  int* row_f = (int*)(lastcol + 8 * BN * 32);   // BN+2
  int* row_b = row_f + (BN + 2);                // BN+2
  int* cur_f = row_b + (BN + 2);                // BN*NBKT
  int* cur_b = cur_f + BN * NBKT;               // BN*NBKT
  int4* ce_f = (int4*)(cur_b + BN * NBKT);      // NE int4
  int4* ce_b = ce_f + NE;                       // NE int4
  unsigned short* SWb  = (unsigned short*)(ce_b + NE);  // 65536 halves
  unsigned short* W0T  = SWb + 65536;                   // 131072 halves
  unsigned short* W1T  = W0T + 131072;                  // 8192 halves
  unsigned short* Gg16 = W1T + 8192;                    // 49152 halves
  unsigned short* WTC  = Gg16 + 49152;                  // 32768 halves
  float* bsumv = (float*)(WTC + 32768);                 // 256 f32

  hipMemsetAsync(cur_f, 0, 2 * BN * NBKT * sizeof(int), stream);
  const int egrid = (NE + 255) / 256;
  k_count<<<egrid, 256, 0, stream>>>(esrc, edst, cur_f, cur_b);
  k_scan<<<1, 1024, 0, stream>>>(cur_f, row_f, cur_b, row_b);
  k_fill<<<egrid, 256, 0, stream>>>(esrc, edst, ew, cur_f, ce_f, cur_b, ce_b);
  k_init<<<(BN * 13 * 32 + 255) / 256, 256, 0, stream>>>(x, init_w, init_b, hA);
  k_pack<<<512, 256, 0, stream>>>(skip_w, skip_b, w0, w1, gcn_w, filt_w, gate_w,
                                  SWb, W0T, W1T, bsumv, Gg16, WTC);

  // layer 0 TCN (standalone)
  k_tcn<13, 1, 12><<<BN / 8, 256, 0, stream>>>(hA, tA, filt_w, filt_b, gate_w, gate_b);

  // fused layers: agg(l) + TCN(l+1)
#define FUSED(l, LOUTv, Dv, TPv, D2v, TP2v, LASTv, tin, tout, hin, hout) \
  k_fused<LOUTv, Dv, TPv, D2v, TP2v, LASTv><<<BN / 4, 128, 0, stream>>>( \
      tin, hin, hout, lastcol + l * BN * 32, tout, row_f, ce_f, row_b, ce_b, \
      Gg16 + l * 6144, gcn_b + l * 32, WTC + (l + 1) * 4096, \
      filt_b + (l + 1) * 32, gate_b + (l + 1) * 32);

  FUSED(0, 12, 1, 12, 2, 12, false, tA, tB, hA, hB)
  FUSED(1, 10, 2, 12, 1, 12, false, tB, tA, hB, hA)
  FUSED(2,  9, 1, 12, 2,  8, false, tA, tB, hA, hB)
  FUSED(3,  7, 2,  8, 1,  8, false, tB, tA, hB, hA)
  FUSED(4,  6, 1,  8, 2,  4, false, tA, tB, hA, hB)
  FUSED(5,  4, 2,  4, 1,  4, false, tB, tA, hB, hA)
  FUSED(6,  3, 1,  4, 2,  4, false, tA, tB, hA, hB)
#undef FUSED
  // last layer: agg only
  k_fused<1, 2, 4, 2, 4, true><<<BN / 4, 128, 0, stream>>>(
      tB, hB, hA, lastcol + 7 * BN * 32, tA, row_f, ce_f, row_b, ce_b,
      Gg16 + 7 * 6144, gcn_b + 7 * 32, WTC, filt_b, gate_b);

  k_final<<<BN / 32, 256, 0, stream>>>(lastcol, SWb, W0T, W1T, bsumv, b0, b1, out);
}

// Round 12
// 620.776 us; speedup vs baseline: 1.6138x; 1.6138x over previous
//
#include <hip/hip_runtime.h>
#include <hip/hip_fp16.h>

#define BN 13248
#define NE 211968
#define NBKT 8        // source buckets (src>>11); approx locality sort
#define SCAN_TOT (BN * NBKT)   // 105984
#define SCAN_NBLK 52           // 52 * 2048 = 106496 >= SCAN_TOT
#define ZSTRIDE 200   // halves per Z row (192 + 8 pad)
#define HSTRIDE 40    // halves per hb16 tau-row (32 + 8 pad)
#define HNODE 480     // 12 rows * 40

typedef __attribute__((ext_vector_type(8))) short bf16x8;
typedef __attribute__((ext_vector_type(8))) _Float16 f16x8;
typedef __attribute__((ext_vector_type(4))) float f32x4;

__device__ __forceinline__ f32x4 mfma16b(bf16x8 a, bf16x8 b, f32x4 c) {
  return __builtin_amdgcn_mfma_f32_16x16x32_bf16(a, b, c, 0, 0, 0);
}
__device__ __forceinline__ f32x4 mfma16h(f16x8 a, f16x8 b, f32x4 c) {
  return __builtin_amdgcn_mfma_f32_16x16x32_f16(a, b, c, 0, 0, 0);
}

__device__ __forceinline__ unsigned short to_bf16(float v) {
  unsigned bits = __float_as_uint(v);
  return (unsigned short)((bits + 0x7FFFu + ((bits >> 16) & 1u)) >> 16);
}
__device__ __forceinline__ unsigned short to_f16(float v) {
  union { __half h; unsigned short s; } u; u.h = __float2half(v); return u.s;
}
__device__ __forceinline__ unsigned h2u(__half2 h) {
  union { __half2 h; unsigned u; } v; v.h = h; return v.u;
}
__device__ __forceinline__ __half2 u2h(unsigned u) {
  union { unsigned u; __half2 h; } v; v.u = u; return v.h;
}

__device__ __forceinline__ float fast_tanh(float x) {
  float e2 = __expf(2.f * x);
  return 1.f - 2.f / (e2 + 1.f);
}
__device__ __forceinline__ float fast_sig(float x) {
  return 1.f / (1.f + __expf(-x));
}

// ---------------- CSR build (bucketed by source octile for L2 locality) ----------------
__global__ void k_count(const int* __restrict__ src, const int* __restrict__ dst,
                        int* __restrict__ cur_f, int* __restrict__ cur_b) {
  int e = blockIdx.x * 256 + threadIdx.x;
  if (e < NE) {
    int s = src[e], t = dst[e];
    atomicAdd(&cur_f[t * NBKT + (s >> 11)], 1);
    atomicAdd(&cur_b[s * NBKT + (t >> 11)], 1);
  }
}

// phase 1: per-block local exclusive scan (2048 entries/block) + block totals
__global__ __launch_bounds__(1024) void k_scan1(int* __restrict__ cnt_f, int* __restrict__ cnt_b,
                                                int* __restrict__ bsum) {
  __shared__ int sdata[1024];
  int b = blockIdx.x;
  int dir = (b >= SCAN_NBLK) ? 1 : 0;
  int lb = dir ? b - SCAN_NBLK : b;
  int* cnt = dir ? cnt_b : cnt_f;
  int tid = threadIdx.x;
  int i0 = lb * 2048 + tid * 2;
  int v0 = (i0 < SCAN_TOT) ? cnt[i0] : 0;
  int v1 = (i0 + 1 < SCAN_TOT) ? cnt[i0 + 1] : 0;
  int tot = v0 + v1;
  sdata[tid] = tot;
  __syncthreads();
  for (int off = 1; off < 1024; off <<= 1) {
    int add = (tid >= off) ? sdata[tid - off] : 0;
    __syncthreads();
    sdata[tid] += add;
    __syncthreads();
  }
  int excl = sdata[tid] - tot;
  if (i0 < SCAN_TOT) cnt[i0] = excl;
  if (i0 + 1 < SCAN_TOT) cnt[i0 + 1] = excl + v0;
  if (tid == 1023) bsum[b] = sdata[1023];
}

// phase 2: segmented exclusive scan of the 2*SCAN_NBLK block totals
__global__ void k_scan2(int* __restrict__ bsum) {
  __shared__ int sdata[128];
  int tid = threadIdx.x;
  int seg = (tid >= 64) ? 64 : 0;          // fwd totals in 0..51, bwd in 64..115
  int src = (tid < 64) ? tid : tid - 64 + SCAN_NBLK;
  int valid = ((tid & 63) < SCAN_NBLK);
  int v = valid ? bsum[src] : 0;
  sdata[tid] = v;
  __syncthreads();
  for (int off = 1; off < 64; off <<= 1) {
    int add = (tid - off >= seg) ? sdata[tid - off] : 0;
    __syncthreads();
    sdata[tid] += add;
    __syncthreads();
  }
  if (valid) bsum[src] = sdata[tid] - v;   // exclusive
}

// phase 3: add block offsets, emit row[] at node boundaries
__global__ __launch_bounds__(1024) void k_scan3(int* __restrict__ cnt_f, int* __restrict__ cnt_b,
                                                const int* __restrict__ bsum,
                                                int* __restrict__ row_f, int* __restrict__ row_b) {
  int b = blockIdx.x;
  int dir = (b >= SCAN_NBLK) ? 1 : 0;
  int lb = dir ? b - SCAN_NBLK : b;
  int* cnt = dir ? cnt_b : cnt_f;
  int* row = dir ? row_b : row_f;
  int off = bsum[b];
  int tid = threadIdx.x;
#pragma unroll
  for (int k = 0; k < 2; ++k) {
    int idx = lb * 2048 + tid * 2 + k;
    if (idx < SCAN_TOT) {
      int v = cnt[idx] + off;
      cnt[idx] = v;
      if ((idx & (NBKT - 1)) == 0) row[idx / NBKT] = v;
    }
  }
  if (b == 0 && tid == 0) { row_f[BN] = NE; row_b[BN] = NE; }
}

// edge record: {col, h2(w), h2(w^2), h2(w^3)}
__global__ void k_fill(const int* __restrict__ src, const int* __restrict__ dst,
                       const float* __restrict__ w,
                       int* __restrict__ cur_f, int4* __restrict__ ce_f,
                       int* __restrict__ cur_b, int4* __restrict__ ce_b) {
  int e = blockIdx.x * 256 + threadIdx.x;
  if (e < NE) {
    int s = src[e], t = dst[e];
    float wv = w[e];
    float w2 = wv * wv, w3 = w2 * wv;
    int u1 = (int)h2u(__float2half2_rn(wv));
    int u2 = (int)h2u(__float2half2_rn(w2));
    int u3 = (int)h2u(__float2half2_rn(w3));
    int p = atomicAdd(&cur_f[t * NBKT + (s >> 11)], 1); ce_f[p] = make_int4(s, u1, u2, u3);
    int q = atomicAdd(&cur_b[s * NBKT + (t >> 11)], 1); ce_b[q] = make_int4(t, u1, u2, u3);
  }
}

// ---------------- init linear ----------------
__global__ void k_init(const float* __restrict__ x, const float* __restrict__ iw,
                       const float* __restrict__ ib, float* __restrict__ h) {
  int idx = blockIdx.x * 256 + threadIdx.x;
  if (idx >= BN * 13 * 32) return;
  int c = idx & 31;
  int r = idx >> 5;          // r = tau*BN + n
  int n = r % BN;
  int tau = r / BN;
  float x0 = x[(n * 13 + tau) * 2 + 0];
  float x1 = x[(n * 13 + tau) * 2 + 1];
  h[idx] = fmaf(x0, iw[c], fmaf(x1, iw[32 + c], ib[c]));
}

// ---------------- weight pre-pack ----------------
__global__ void k_pack(const float* __restrict__ skip_w, const float* __restrict__ skip_b,
                       const float* __restrict__ w0, const float* __restrict__ w1,
                       const float* __restrict__ gcn_w,
                       const float* __restrict__ filt_w, const float* __restrict__ gate_w,
                       unsigned short* __restrict__ SWb, unsigned short* __restrict__ W0T,
                       unsigned short* __restrict__ W1T, float* __restrict__ bsum,
                       unsigned short* __restrict__ Gg16, unsigned short* __restrict__ WTC) {
  int id = blockIdx.x * 256 + threadIdx.x;
  if (id < 65536) {          // SWb[j][k=l*32+c] = skip_w[l][j][c]  (bf16, head)
    int j = id >> 8, k = id & 255;
    SWb[id] = to_bf16(skip_w[((k >> 5) * 256 + j) * 32 + (k & 31)]);
  }
  if (id < 131072) {         // W0T[jo][k] = w0[k][jo]  (bf16, head)
    int jo = id >> 8, k = id & 255;
    W0T[id] = to_bf16(w0[k * 512 + jo]);
  }
  if (id < 8192) {           // W1T[n][k] = w1[k][n], n padded to 16  (bf16, head)
    int n = id >> 9, k = id & 511;
    W1T[id] = (n < 12) ? to_bf16(w1[k * 12 + n]) : (unsigned short)0;
  }
  if (id < 256) {
    float s = 0.f;
    for (int l = 0; l < 8; ++l) s += skip_b[l * 256 + id];
    bsum[id] = s;
  }
  if (id < 49152) {          // Gg16[l][co][k=a*32+ci] = gcn_w[l][a][ci][co]  (fp16)
    int l = id / 6144, rem = id % 6144;
    int co = rem / 192, k = rem % 192;
    int a = k >> 5, ci = k & 31;
    Gg16[id] = to_f16(gcn_w[((l * 6 + a) * 32 + ci) * 32 + co]);
  }
  if (id < 32768) {          // WTC[l][g][co][k=64]: B^T for TCN MFMA (fp16)
    int l = id >> 12, rem = id & 4095;
    int g = rem >> 11, co = (rem >> 6) & 31, k = rem & 63;
    const float* srcw = (g ? gate_w : filt_w) + l * 2048;
    float v = (k < 32) ? srcw[(co * 32 + k) * 2 + 0] : srcw[(co * 32 + (k - 32)) * 2 + 1];
    WTC[id] = to_f16(v);
  }
}

// ---------------- standalone gated TCN (layer 0 only): fp16 t out ----------------
template<int LIN, int D, int TPAD>
__global__ __launch_bounds__(256) void k_tcn(const float* __restrict__ h_in, unsigned short* __restrict__ t_out,
    const float* __restrict__ fw, const float* __restrict__ fb,
    const float* __restrict__ gw, const float* __restrict__ gb) {
  constexpr int LOUT = LIN - D;
  __shared__ __align__(16) float wq[32 * 32 * 4];
  __shared__ float hl[8][LIN * 32];
  int tid = threadIdx.x;
  for (int f = tid; f < 4096; f += 256) {
    int e = f & 3, co = (f >> 2) & 31, ci = f >> 7;
    const float* srcw = (e < 2) ? fw : gw;
    wq[f] = srcw[(co * 32 + ci) * 2 + (e & 1)];
  }
  int n0 = blockIdx.x * 8;
  for (int i = tid; i < 8 * LIN * 32; i += 256) {
    int c = i & 31, r = i >> 5;
    int nl = r / LIN, tau = r % LIN;
    hl[nl][tau * 32 + c] = h_in[(tau * BN + n0 + nl) * 32 + c];
  }
  __syncthreads();
  int nl = tid >> 5, co = tid & 31;
  int n = n0 + nl;
  float accf[LOUT], accg[LOUT];
  float fbv = fb[co], gbv = gb[co];
#pragma unroll
  for (int j = 0; j < LOUT; ++j) { accf[j] = fbv; accg[j] = gbv; }
#pragma unroll
  for (int ci = 0; ci < 32; ++ci) {
    float4 wv = *(const float4*)&wq[(ci * 32 + co) * 4];
    float xr[LIN];
#pragma unroll
    for (int t = 0; t < LIN; ++t) xr[t] = hl[nl][t * 32 + ci];
#pragma unroll
    for (int j = 0; j < LOUT; ++j) {
      accf[j] = fmaf(xr[j], wv.x, accf[j]);
      accf[j] = fmaf(xr[j + D], wv.y, accf[j]);
      accg[j] = fmaf(xr[j], wv.z, accg[j]);
      accg[j] = fmaf(xr[j + D], wv.w, accg[j]);
    }
  }
#pragma unroll
  for (int j = 0; j < TPAD; ++j) {
    unsigned short v = 0;
    if (j < LOUT) v = to_f16(fast_tanh(accf[j < LOUT ? j : 0]) * fast_sig(accg[j < LOUT ? j : 0]));
    t_out[(n * TPAD + j) * 32 + co] = v;
  }
}

// ---------------- gather: skip loads of known-zero padded rows ----------------
template<int TPAD, int NT>
__device__ __forceinline__ void edge_fma(const int4& c, const uint2 (&u)[NT], __half2* A) {
  __half2 wh0 = u2h((unsigned)c.y), wh1 = u2h((unsigned)c.z), wh2 = u2h((unsigned)c.w);
#pragma unroll
  for (int j = 0; j < NT; ++j) {
    __half2 v0 = u2h(u[j].x), v1 = u2h(u[j].y);
    A[(0 * NT + j) * 2 + 0] = __hfma2(wh0, v0, A[(0 * NT + j) * 2 + 0]);
    A[(0 * NT + j) * 2 + 1] = __hfma2(wh0, v1, A[(0 * NT + j) * 2 + 1]);
    A[(1 * NT + j) * 2 + 0] = __hfma2(wh1, v0, A[(1 * NT + j) * 2 + 0]);
    A[(1 * NT + j) * 2 + 1] = __hfma2(wh1, v1, A[(1 * NT + j) * 2 + 1]);
    A[(2 * NT + j) * 2 + 0] = __hfma2(wh2, v0, A[(2 * NT + j) * 2 + 0]);
    A[(2 * NT + j) * 2 + 1] = __hfma2(wh2, v1, A[(2 * NT + j) * 2 + 1]);
  }
}

template<int TPAD, int NT, int LOUTT>
__device__ __forceinline__ void gather_dir(const unsigned short* __restrict__ t_in,
    int e0, int e1, const int4* __restrict__ ce, int rowoff0, int rowbase, __half2* A) {
  constexpr bool FULL = (LOUTT >= TPAD);
  constexpr int EB = 4;
  int e = e0;
  for (; e + EB <= e1; e += EB) {
    int4 c[EB];
    uint2 u[EB][NT];
#pragma unroll
    for (int k = 0; k < EB; ++k) c[k] = ce[e + k];
#pragma unroll
    for (int k = 0; k < EB; ++k) {
      const unsigned short* p = t_in + c[k].x * (TPAD * 32) + rowoff0;
#pragma unroll
      for (int j = 0; j < NT; ++j) {
        if (FULL || rowbase + j < LOUTT) u[k][j] = *(const uint2*)(p + j * 32);
        else u[k][j] = make_uint2(0u, 0u);
      }
    }
#pragma unroll
    for (int k = 0; k < EB; ++k) edge_fma<TPAD, NT>(c[k], u[k], A);
  }
  for (; e < e1; ++e) {
    int4 c = ce[e];
    uint2 u[NT];
    const unsigned short* p = t_in + c.x * (TPAD * 32) + rowoff0;
#pragma unroll
    for (int j = 0; j < NT; ++j) {
      if (FULL || rowbase + j < LOUTT) u[j] = *(const uint2*)(p + j * 32);
      else u[j] = make_uint2(0u, 0u);
    }
    edge_fma<TPAD, NT>(c, u, A);
  }
}

// ---------------- fused layer: agg (MFMA f16) + residual + next-layer TCN (MFMA f16) ----------------
template<int LOUT, int D, int TPAD, int D2, int TPAD2, bool LAST>
__global__ __launch_bounds__(128, 4) void k_fused(
    const unsigned short* __restrict__ t_in,
    const float* __restrict__ h_in, float* __restrict__ h_out,
    float* __restrict__ lastcol, unsigned short* __restrict__ t_next,
    const int* __restrict__ row_f, const int4* __restrict__ ce_f,
    const int* __restrict__ row_b, const int4* __restrict__ ce_b,
    const unsigned short* __restrict__ Wg,    // [32][192] fp16 B^T (agg)
    const float* __restrict__ bias,
    const unsigned short* __restrict__ Wtc,   // [2][32][64] fp16 B^T (next TCN)
    const float* __restrict__ fbn, const float* __restrict__ gbn) {
  constexpr int NT = TPAD / 4;
  constexpr int LOUT2 = LAST ? 1 : (LOUT - D2);
  constexpr int SBYTES = 4 * TPAD * ZSTRIDE * 2;
  __shared__ __align__(16) char smem[SBYTES];
  unsigned short* Zl = (unsigned short*)smem;
  unsigned short* hb16 = (unsigned short*)smem;    // reused after agg-MFMA
  int tid = threadIdx.x;
  int nl = tid >> 5, lane32 = tid & 31;
  int tl = lane32 >> 3;
  int c4 = (lane32 & 7) << 2;
  int n0 = blockIdx.x * 4;
  int n = n0 + nl;
  int rowbase = tl * NT;
  int rowoff0 = rowbase * 32 + c4;
  int ef0 = row_f[n], ef1 = row_f[n + 1];
  int eb0 = row_b[n], eb1 = row_b[n + 1];
  __half2 acc[6 * NT * 2];
  __half2 zero = __float2half2_rn(0.f);
#pragma unroll
  for (int i = 0; i < 6 * NT * 2; ++i) acc[i] = zero;
  gather_dir<TPAD, NT, LOUT>(t_in, ef0, ef1, ce_f, rowoff0, rowbase, acc);
  gather_dir<TPAD, NT, LOUT>(t_in, eb0, eb1, ce_b, rowoff0, rowbase, acc + 3 * NT * 2);
#pragma unroll
  for (int j = 0; j < NT; ++j) {
    int m = nl * TPAD + rowbase + j;
#pragma unroll
    for (int a = 0; a < 6; ++a) {
      uint2 v = make_uint2(h2u(acc[(a * NT + j) * 2 + 0]), h2u(acc[(a * NT + j) * 2 + 1]));
      *(uint2*)(&Zl[m * ZSTRIDE + a * 32 + c4]) = v;
    }
  }
  __syncthreads();
  // agg MFMA: D[4*TPAD rows][32 co] = Z[4*TPAD][192] @ Wg[192][32]
  int wave = tid >> 6, lane = tid & 63;
  int m16 = lane & 15, q = lane >> 4;
  f32x4 dacc[NT];
#pragma unroll
  for (int i = 0; i < NT; ++i) {
    int u = wave * NT + i;
    int mt = u >> 1, nt = u & 1;
    dacc[i] = (f32x4){0.f, 0.f, 0.f, 0.f};
#pragma unroll
    for (int ks = 0; ks < 6; ++ks) {
      f16x8 av = *(const f16x8*)(&Zl[(mt * 16 + m16) * ZSTRIDE + ks * 32 + q * 8]);
      f16x8 bv = *(const f16x8*)((const _Float16*)Wg + (nt * 16 + m16) * 192 + ks * 32 + q * 8);
      dacc[i] = mfma16h(av, bv, dacc[i]);
    }
  }
  __syncthreads();   // Zl dead; smem becomes hb16
#pragma unroll
  for (int i = 0; i < NT; ++i) {
    int u = wave * NT + i;
    int mt = u >> 1, nt = u & 1;
    int co = nt * 16 + m16;
    float bco = bias[co];
#pragma unroll
    for (int r = 0; r < 4; ++r) {
      int mm = mt * 16 + q * 4 + r;           // C/D: col=lane&15, row=q*4+r
      int node = mm / TPAD;
      int tau = mm % TPAD;
      if (tau < LOUT) {
        float rres = h_in[((tau + D) * BN + n0 + node) * 32 + co];
        float o = dacc[i][r] + bco + rres;
        h_out[(tau * BN + n0 + node) * 32 + co] = o;
        if (!LAST) hb16[node * HNODE + tau * HSTRIDE + co] = to_f16(o);
        if (tau == LOUT - 1) lastcol[(n0 + node) * 32 + co] = o;
      }
    }
  }
  if (!LAST) {
    __syncthreads();
    // TCN via MFMA: A row m16 = j (conv out step), K=64: [h[j][ci], h[j+D2][ci]]
#pragma unroll
    for (int i = 0; i < 4; ++i) {
      int u = wave * 4 + i;
      int node = u >> 1, ntc = u & 1;
      int co = ntc * 16 + m16;
      f32x4 df = (f32x4){0.f, 0.f, 0.f, 0.f};
      f32x4 dg = (f32x4){0.f, 0.f, 0.f, 0.f};
#pragma unroll
      for (int s = 0; s < 2; ++s) {
        f16x8 av = *(const f16x8*)(&hb16[node * HNODE + (m16 + s * D2) * HSTRIDE + q * 8]);
        f16x8 bvf = *(const f16x8*)((const _Float16*)Wtc + (0 * 32 + co) * 64 + s * 32 + q * 8);
        f16x8 bvg = *(const f16x8*)((const _Float16*)Wtc + (1 * 32 + co) * 64 + s * 32 + q * 8);
        df = mfma16h(av, bvf, df);
        dg = mfma16h(av, bvg, dg);
      }
      float fbv = fbn[co], gbv = gbn[co];
#pragma unroll
      for (int r = 0; r < 4; ++r) {
        int j = q * 4 + r;
        if (j < TPAD2) {
          unsigned short v = 0;
          if (j < LOUT2)
            v = to_f16(fast_tanh(df[r] + fbv) * fast_sig(dg[r] + gbv));
          t_next[((n0 + node) * TPAD2 + j) * 32 + co] = v;
        }
      }
    }
  }
}

// ------------- fused MFMA head (bf16) -------------
__device__ __forceinline__ bf16x8 ldsA(const unsigned short* buf, int stride, int row, int ks, int q) {
  int unit = ks * 4 + q;
  int addr = row * stride + ((unit ^ (row & 7)) << 3);
  return *(const bf16x8*)(buf + addr);
}

__global__ __launch_bounds__(256) void k_final(const float* __restrict__ lastcol,
    const unsigned short* __restrict__ SWb, const unsigned short* __restrict__ W0T,
    const unsigned short* __restrict__ W1T, const float* __restrict__ bsum,
    const float* __restrict__ b0, const float* __restrict__ b1,
    float* __restrict__ out) {
  __shared__ __align__(16) unsigned short Z[32 * 256];
  __shared__ __align__(16) unsigned short H[32 * 512];
  int tid = threadIdx.x;
  int wave = tid >> 6, lane = tid & 63;
  int m16 = lane & 15, q = lane >> 4;
  int n0 = blockIdx.x * 32;
#pragma unroll
  for (int it = 0; it < 32; ++it) {
    int id = it * 256 + tid;
    int m = id >> 8, k = id & 255;
    float v = lastcol[((k >> 5) * BN + n0 + m) * 32 + (k & 31)];
    Z[m * 256 + (((k >> 3) ^ (m & 7)) << 3) + (k & 7)] = to_bf16(v);
  }
  __syncthreads();
  f32x4 acc1[2][4];
#pragma unroll
  for (int mt = 0; mt < 2; ++mt)
#pragma unroll
    for (int i = 0; i < 4; ++i) acc1[mt][i] = (f32x4){0.f, 0.f, 0.f, 0.f};
#pragma unroll
  for (int ks = 0; ks < 8; ++ks) {
    bf16x8 a0 = ldsA(Z, 256, m16, ks, q);
    bf16x8 a1 = ldsA(Z, 256, 16 + m16, ks, q);
#pragma unroll
    for (int i = 0; i < 4; ++i) {
      int j = (wave * 4 + i) * 16 + m16;
      bf16x8 b = *(const bf16x8*)(SWb + j * 256 + ks * 32 + q * 8);
      acc1[0][i] = mfma16b(a0, b, acc1[0][i]);
      acc1[1][i] = mfma16b(a1, b, acc1[1][i]);
    }
  }
  __syncthreads();
#pragma unroll
  for (int i = 0; i < 4; ++i) {
    int j = (wave * 4 + i) * 16 + m16;
    float bs = bsum[j];
#pragma unroll
    for (int mt = 0; mt < 2; ++mt)
#pragma unroll
      for (int r = 0; r < 4; ++r) {
        int row = mt * 16 + q * 4 + r;
        float v = fmaxf(acc1[mt][i][r] + bs, 0.f);
        Z[row * 256 + (((j >> 3) ^ (row & 7)) << 3) + (j & 7)] = to_bf16(v);
      }
  }
  __syncthreads();
  f32x4 acc2[2][8];
#pragma unroll
  for (int mt = 0; mt < 2; ++mt)
#pragma unroll
    for (int i = 0; i < 8; ++i) acc2[mt][i] = (f32x4){0.f, 0.f, 0.f, 0.f};
#pragma unroll
  for (int ks = 0; ks < 8; ++ks) {
    bf16x8 a0 = ldsA(Z, 256, m16, ks, q);
    bf16x8 a1 = ldsA(Z, 256, 16 + m16, ks, q);
#pragma unroll
    for (int i = 0; i < 8; ++i) {
      int jo = (wave * 8 + i) * 16 + m16;
      bf16x8 b = *(const bf16x8*)(W0T + jo * 256 + ks * 32 + q * 8);
      acc2[0][i] = mfma16b(a0, b, acc2[0][i]);
      acc2[1][i] = mfma16b(a1, b, acc2[1][i]);
    }
  }
#pragma unroll
  for (int i = 0; i < 8; ++i) {
    int jo = (wave * 8 + i) * 16 + m16;
    float b0v = b0[jo];
#pragma unroll
    for (int mt = 0; mt < 2; ++mt)
#pragma unroll
      for (int r = 0; r < 4; ++r) {
        int row = mt * 16 + q * 4 + r;
        float v = fmaxf(acc2[mt][i][r] + b0v, 0.f);
        H[row * 512 + (((jo >> 3) ^ (row & 7)) << 3) + (jo & 7)] = to_bf16(v);
      }
  }
  __syncthreads();
  if (wave < 2) {
    f32x4 acc3 = (f32x4){0.f, 0.f, 0.f, 0.f};
#pragma unroll
    for (int ks = 0; ks < 16; ++ks) {
      bf16x8 a = ldsA(H, 512, wave * 16 + m16, ks, q);
      bf16x8 b = *(const bf16x8*)(W1T + m16 * 512 + ks * 32 + q * 8);
      acc3 = mfma16b(a, b, acc3);
    }
    if (m16 < 12) {
      float bv = b1[m16];
#pragma unroll
      for (int r = 0; r < 4; ++r)
        out[(n0 + wave * 16 + q * 4 + r) * 12 + m16] = acc3[r] + bv;
    }
  }
}

extern "C" void kernel_launch(void* const* d_in, const int* in_sizes, int n_in,
                              void* d_out, int out_size, void* d_ws, size_t ws_size,
                              hipStream_t stream) {
  const float* x      = (const float*)d_in[0];
  const int*   esrc   = (const int*)d_in[1];
  const int*   edst   = (const int*)d_in[2];
  const float* ew     = (const float*)d_in[3];
  const float* init_w = (const float*)d_in[4];
  const float* init_b = (const float*)d_in[5];
  const float* filt_w = (const float*)d_in[6];
  const float* filt_b = (const float*)d_in[7];
  const float* gate_w = (const float*)d_in[8];
  const float* gate_b = (const float*)d_in[9];
  const float* gcn_w  = (const float*)d_in[10];
  const float* gcn_b  = (const float*)d_in[11];
  const float* skip_w = (const float*)d_in[12];
  const float* skip_b = (const float*)d_in[13];
  const float* w0     = (const float*)d_in[14];
  const float* b0     = (const float*)d_in[15];
  const float* w1     = (const float*)d_in[16];
  const float* b1     = (const float*)d_in[17];
  float* out = (float*)d_out;

  float* base = (float*)d_ws;
  float* hA      = base;                        // 13*BN*32 f32
  float* hB      = hA + 13 * BN * 32;           // 13*BN*32 f32
  unsigned short* tA = (unsigned short*)(hB + 13 * BN * 32);  // 12*BN*32 halves
  unsigned short* tB = tA + 12 * BN * 32;                     // 12*BN*32 halves
  float* lastcol = (float*)(tB + 12 * BN * 32); // 8*BN*32 f32
  int* row_f = (int*)(lastcol + 8 * BN * 32);   // BN+2
  int* row_b = row_f + (BN + 2);                // BN+2
  int* bscan = row_b + (BN + 2);                // 2*SCAN_NBLK (+pad)
  int* cur_f = bscan + 128;                     // BN*NBKT
  int* cur_b = cur_f + BN * NBKT;               // BN*NBKT
  int4* ce_f = (int4*)(cur_b + BN * NBKT);      // NE int4
  int4* ce_b = ce_f + NE;                       // NE int4
  unsigned short* SWb  = (unsigned short*)(ce_b + NE);  // 65536 halves
  unsigned short* W0T  = SWb + 65536;                   // 131072 halves
  unsigned short* W1T  = W0T + 131072;                  // 8192 halves
  unsigned short* Gg16 = W1T + 8192;                    // 49152 halves
  unsigned short* WTC  = Gg16 + 49152;                  // 32768 halves
  float* bsumv = (float*)(WTC + 32768);                 // 256 f32

  hipMemsetAsync(cur_f, 0, 2 * BN * NBKT * sizeof(int), stream);
  const int egrid = (NE + 255) / 256;
  k_count<<<egrid, 256, 0, stream>>>(esrc, edst, cur_f, cur_b);
  k_scan1<<<2 * SCAN_NBLK, 1024, 0, stream>>>(cur_f, cur_b, bscan);
  k_scan2<<<1, 128, 0, stream>>>(bscan);
  k_scan3<<<2 * SCAN_NBLK, 1024, 0, stream>>>(cur_f, cur_b, bscan, row_f, row_b);
  k_fill<<<egrid, 256, 0, stream>>>(esrc, edst, ew, cur_f, ce_f, cur_b, ce_b);
  k_init<<<(BN * 13 * 32 + 255) / 256, 256, 0, stream>>>(x, init_w, init_b, hA);
  k_pack<<<512, 256, 0, stream>>>(skip_w, skip_b, w0, w1, gcn_w, filt_w, gate_w,
                                  SWb, W0T, W1T, bsumv, Gg16, WTC);

  // layer 0 TCN (standalone)
  k_tcn<13, 1, 12><<<BN / 8, 256, 0, stream>>>(hA, tA, filt_w, filt_b, gate_w, gate_b);

  // fused layers: agg(l) + TCN(l+1)
#define FUSED(l, LOUTv, Dv, TPv, D2v, TP2v, LASTv, tin, tout, hin, hout) \
  k_fused<LOUTv, Dv, TPv, D2v, TP2v, LASTv><<<BN / 4, 128, 0, stream>>>( \
      tin, hin, hout, lastcol + l * BN * 32, tout, row_f, ce_f, row_b, ce_b, \
      Gg16 + l * 6144, gcn_b + l * 32, WTC + (l + 1) * 4096, \
      filt_b + (l + 1) * 32, gate_b + (l + 1) * 32);

  FUSED(0, 12, 1, 12, 2, 12, false, tA, tB, hA, hB)
  FUSED(1, 10, 2, 12, 1, 12, false, tB, tA, hB, hA)
  FUSED(2,  9, 1, 12, 2,  8, false, tA, tB, hA, hB)
  FUSED(3,  7, 2,  8, 1,  8, false, tB, tA, hB, hA)
  FUSED(4,  6, 1,  8, 2,  4, false, tA, tB, hA, hB)
  FUSED(5,  4, 2,  4, 1,  4, false, tB, tA, hB, hA)
  FUSED(6,  3, 1,  4, 2,  4, false, tA, tB, hA, hB)
#undef FUSED
  // last layer: agg only
  k_fused<1, 2, 4, 2, 4, true><<<BN / 4, 128, 0, stream>>>(
      tB, hB, hA, lastcol + 7 * BN * 32, tA, row_f, ce_f, row_b, ce_b,
      Gg16 + 7 * 6144, gcn_b + 7 * 32, WTC, filt_b, gate_b);

  k_final<<<BN / 32, 256, 0, stream>>>(lastcol, SWb, W0T, W1T, bsumv, b0, b1, out);
}